// Round 9
// baseline (12148.895 us; speedup 1.0000x reference)
//
#include <hip/hip_runtime.h>
#include <cmath>

constexpr int cB = 512, cT = 64, cD = 512, cH = 8, cDH = 64, cFF = 2048;
constexpr float cSCALE = 0.125f;  // DH^-0.5

typedef short bfrag __attribute__((ext_vector_type(8)));   // 8 bf16 = 4 VGPRs
typedef float f32x4 __attribute__((ext_vector_type(4)));

__device__ __forceinline__ short f2bf(float x) {
  union { float f; unsigned u; } v{x};
  unsigned r = v.u + 0x7fff + ((v.u >> 16) & 1);
  return (short)(r >> 16);
}
__device__ __forceinline__ float bf2f(short s) {
  union { unsigned u; float f; } v;
  v.u = ((unsigned)(unsigned short)s) << 16;
  return v.f;
}
__device__ __forceinline__ float sigm(float z) { return 1.f / (1.f + __expf(-z)); }

// async global->LDS: lane l's 16B land at dst + l*16 (wave-uniform dst)
__device__ __forceinline__ void stage_tile(const short* wt, int row0, int ldw,
                                           int koff, short* dst, int lane) {
  const short* src = wt + (size_t)(row0 + (lane & 15)) * ldw + koff + (lane >> 4) * 8;
  __builtin_amdgcn_global_load_lds(
      (const __attribute__((address_space(1))) void*)src,
      (__attribute__((address_space(3))) void*)dst, 16, 0, 0);
}

// ======================= standalone GEMMs (prep / epilogue) =================
enum GemmMode { MQ = 0, MWO, MFF1, MFF2 };

struct GemmArgs {
  const float *A, *A2, *sm, *sr, *g, *b;
  const short *WT, *WT2;   // hi / lo
  const float *bias, *extra;
  float *O;
  short *Os;
};

template<int MODE>
__device__ __forceinline__ float loadA(const GemmArgs& p, int r, int k) {
  if constexpr (MODE == MQ) {
    int t = r >> 9, bb = r & 511;
    float v = (t < cT) ? p.A[((size_t)bb * cT + t) * cD + k]
                       : p.A2[(size_t)bb * cD + k];
    return (v - p.sm[r]) * p.sr[r] * p.g[k] + p.b[k];
  } else if constexpr (MODE == MFF1) {
    return (p.A[(size_t)r * cD + k] - p.sm[r]) * p.sr[r] * p.g[k] + p.b[k];
  } else if constexpr (MODE == MFF2) {
    return p.A[(size_t)r * cFF + k];
  } else {  // MWO
    return p.A[(size_t)r * cD + k];
  }
}

template<int MODE>
__device__ __forceinline__ void epi(const GemmArgs& p, int r, int cn, float acc) {
  if constexpr (MODE == MQ) {
    p.Os[(size_t)r * cD + cn] = f2bf(acc);  // raw q, bf16 (l2n at consumer)
  } else if constexpr (MODE == MWO) {
    p.O[(size_t)r * cD + cn] = p.extra[(size_t)r * cD + cn] + acc + p.bias[cn];
  } else if constexpr (MODE == MFF1) {
    p.O[(size_t)r * cFF + cn] = fmaxf(acc + p.bias[cn], 0.f);
  } else {  // MFF2
    p.O[(size_t)r * cD + cn] = p.extra[(size_t)r * cD + cn] + acc + p.bias[cn];
  }
}

// single-precision bf16 MFMA GEMM (q_all)
template<int MODE, int LDW>
__global__ __launch_bounds__(256) void mgemm(GemmArgs p, int K) {
  __shared__ short As[64][32];
  __shared__ short Bs[64][32];
  const int tid = threadIdx.x;
  const int lane = tid & 63, wid = tid >> 6;
  const int wm = wid & 1, wn = wid >> 1;
  const int l15 = lane & 15, qd = lane >> 4;
  const int row0 = blockIdx.x * 64;
  const int n0 = blockIdx.y * 64;

  f32x4 acc[2][2] = {};
  const int sm = tid >> 2;
  const int sk = (tid & 3) * 8;

  for (int k0 = 0; k0 < K; k0 += 32) {
    {
      short tmp[8];
#pragma unroll
      for (int j = 0; j < 8; ++j)
        tmp[j] = f2bf(loadA<MODE>(p, row0 + sm, k0 + sk + j));
      *((bfrag*)&As[sm][0] + (sk >> 3)) = *(bfrag*)tmp;
    }
    *((bfrag*)&Bs[sm][0] + (sk >> 3)) =
        *(const bfrag*)(p.WT + (size_t)(n0 + sm) * LDW + k0 + sk);
    __syncthreads();
    bfrag a0 = *((bfrag*)&As[wm * 32 + l15][0] + qd);
    bfrag a1 = *((bfrag*)&As[wm * 32 + 16 + l15][0] + qd);
    bfrag b0 = *((bfrag*)&Bs[wn * 32 + l15][0] + qd);
    bfrag b1 = *((bfrag*)&Bs[wn * 32 + 16 + l15][0] + qd);
    acc[0][0] = __builtin_amdgcn_mfma_f32_16x16x32_bf16(a0, b0, acc[0][0], 0, 0, 0);
    acc[0][1] = __builtin_amdgcn_mfma_f32_16x16x32_bf16(a0, b1, acc[0][1], 0, 0, 0);
    acc[1][0] = __builtin_amdgcn_mfma_f32_16x16x32_bf16(a1, b0, acc[1][0], 0, 0, 0);
    acc[1][1] = __builtin_amdgcn_mfma_f32_16x16x32_bf16(a1, b1, acc[1][1], 0, 0, 0);
    __syncthreads();
  }

#pragma unroll
  for (int fm = 0; fm < 2; ++fm)
#pragma unroll
    for (int fn = 0; fn < 2; ++fn)
#pragma unroll
      for (int rg = 0; rg < 4; ++rg)
        epi<MODE>(p, row0 + wm * 32 + fm * 16 + qd * 4 + rg,
                  n0 + wn * 32 + fn * 16 + l15, acc[fm][fn][rg]);
}

// split-precision GEMM (post-scan layers)
template<int MODE, int LDW>
__global__ __launch_bounds__(256) void pgemm(GemmArgs p, int K) {
  __shared__ short Ah[64][32], Al[64][32];
  __shared__ short Bh[64][32], Bl[64][32];
  const int tid = threadIdx.x;
  const int lane = tid & 63, wid = tid >> 6;
  const int wm = wid & 1, wn = wid >> 1;
  const int l15 = lane & 15, qd = lane >> 4;
  const int row0 = blockIdx.x * 64;
  const int n0 = blockIdx.y * 64;

  f32x4 acc[2][2] = {};
  const int sm = tid >> 2;
  const int sk = (tid & 3) * 8;

  for (int k0 = 0; k0 < K; k0 += 32) {
    {
      short th[8], tl[8];
#pragma unroll
      for (int j = 0; j < 8; ++j) {
        float a = loadA<MODE>(p, row0 + sm, k0 + sk + j);
        short h = f2bf(a);
        th[j] = h;
        tl[j] = f2bf(a - bf2f(h));
      }
      *((bfrag*)&Ah[sm][0] + (sk >> 3)) = *(bfrag*)th;
      *((bfrag*)&Al[sm][0] + (sk >> 3)) = *(bfrag*)tl;
    }
    *((bfrag*)&Bh[sm][0] + (sk >> 3)) =
        *(const bfrag*)(p.WT + (size_t)(n0 + sm) * LDW + k0 + sk);
    *((bfrag*)&Bl[sm][0] + (sk >> 3)) =
        *(const bfrag*)(p.WT2 + (size_t)(n0 + sm) * LDW + k0 + sk);
    __syncthreads();
#pragma unroll
    for (int fm = 0; fm < 2; ++fm) {
      bfrag ah = *((bfrag*)&Ah[wm * 32 + fm * 16 + l15][0] + qd);
      bfrag al = *((bfrag*)&Al[wm * 32 + fm * 16 + l15][0] + qd);
#pragma unroll
      for (int fn = 0; fn < 2; ++fn) {
        bfrag bh = *((bfrag*)&Bh[wn * 32 + fn * 16 + l15][0] + qd);
        bfrag bl = *((bfrag*)&Bl[wn * 32 + fn * 16 + l15][0] + qd);
        acc[fm][fn] = __builtin_amdgcn_mfma_f32_16x16x32_bf16(al, bh, acc[fm][fn], 0, 0, 0);
        acc[fm][fn] = __builtin_amdgcn_mfma_f32_16x16x32_bf16(ah, bl, acc[fm][fn], 0, 0, 0);
        acc[fm][fn] = __builtin_amdgcn_mfma_f32_16x16x32_bf16(ah, bh, acc[fm][fn], 0, 0, 0);
      }
    }
    __syncthreads();
  }

#pragma unroll
  for (int fm = 0; fm < 2; ++fm)
#pragma unroll
    for (int fn = 0; fn < 2; ++fn)
#pragma unroll
      for (int rg = 0; rg < 4; ++rg)
        epi<MODE>(p, row0 + wm * 32 + fm * 16 + qd * 4 + rg,
                  n0 + wn * 32 + fn * 16 + l15, acc[fm][fn][rg]);
}

// ======================= weight transpose + bf16 ============================
__global__ __launch_bounds__(256) void tconv(const float* __restrict__ W,
                                             short* __restrict__ WT, int K, int N) {
  __shared__ float tile[32][33];
  int k0 = blockIdx.x * 32, n0 = blockIdx.y * 32;
  int tx = threadIdx.x & 31, ty = threadIdx.x >> 5;
#pragma unroll
  for (int j = 0; j < 32; j += 8) {
    int k = k0 + ty + j, n = n0 + tx;
    tile[ty + j][tx] = (k < K && n < N) ? W[(size_t)k * N + n] : 0.f;
  }
  __syncthreads();
#pragma unroll
  for (int j = 0; j < 32; j += 8) {
    int n = n0 + ty + j, k = k0 + tx;
    if (n < N && k < K) WT[(size_t)n * K + k] = f2bf(tile[tx][ty + j]);
  }
}

__global__ __launch_bounds__(256) void tconv2(const float* __restrict__ W,
                                              short* __restrict__ WTh,
                                              short* __restrict__ WTl, int K, int N) {
  __shared__ float tile[32][33];
  int k0 = blockIdx.x * 32, n0 = blockIdx.y * 32;
  int tx = threadIdx.x & 31, ty = threadIdx.x >> 5;
#pragma unroll
  for (int j = 0; j < 32; j += 8) {
    int k = k0 + ty + j, n = n0 + tx;
    tile[ty + j][tx] = (k < K && n < N) ? W[(size_t)k * N + n] : 0.f;
  }
  __syncthreads();
#pragma unroll
  for (int j = 0; j < 32; j += 8) {
    int n = n0 + ty + j, k = k0 + tx;
    if (n < N && k < K) {
      float v = tile[tx][ty + j];
      short h = f2bf(v);
      WTh[(size_t)n * K + k] = h;
      WTl[(size_t)n * K + k] = f2bf(v - bf2f(h));
    }
  }
}

// ======================= LN stats + us_norm =================================
__global__ __launch_bounds__(256) void ln_stats_k(
    const float* __restrict__ item_seq, const float* __restrict__ last_item,
    const float* __restrict__ user, const float* __restrict__ n1g,
    const float* __restrict__ n1b, float* __restrict__ lnm,
    float* __restrict__ lnr, float* __restrict__ us_norm) {
  const int lane = threadIdx.x & 63;
  const int w = blockIdx.x * 4 + (threadIdx.x >> 6);
  const float* src;
  int cls, bi = 0;
  if (w < cT * cB) {
    int t = w >> 9, bb = w & 511;
    src = item_seq + ((size_t)bb * cT + t) * cD;
    cls = 0;
  } else if (w < cT * cB + cB) {
    bi = w - cT * cB;
    src = last_item + (size_t)bi * cD;
    cls = 1;
  } else {
    bi = w - cT * cB - cB;
    src = user + (size_t)bi * cD;
    cls = 2;
  }
  float x[8], s = 0.f, ss = 0.f;
#pragma unroll
  for (int i = 0; i < 8; ++i) {
    float v = src[lane + i * 64];
    x[i] = v; s += v; ss += v * v;
  }
#pragma unroll
  for (int o = 32; o >= 1; o >>= 1) { s += __shfl_xor(s, o); ss += __shfl_xor(ss, o); }
  float m = s * (1.f / cD);
  float rstd = rsqrtf(ss * (1.f / cD) - m * m + 1e-5f);
  if (cls == 0) {
    if (lane == 0) { lnm[w] = m; lnr[w] = rstd; }
  } else if (cls == 1) {
    if (lane == 0) { lnm[cT * cB + bi] = m; lnr[cT * cB + bi] = rstd; }
  } else {
#pragma unroll
    for (int i = 0; i < 8; ++i) {
      int d = lane + i * 64;
      us_norm[(size_t)bi * cD + d] = (x[i] - m) * rstd * n1g[d] + n1b[d];
    }
  }
}

// ======================= per-row stats ======================================
__global__ __launch_bounds__(256) void row_stats_k(const float* __restrict__ X,
                                                   float* __restrict__ M,
                                                   float* __restrict__ R) {
  const int lane = threadIdx.x & 63;
  const int w = blockIdx.x * 4 + (threadIdx.x >> 6);
  float s = 0.f, ss = 0.f;
#pragma unroll
  for (int i = 0; i < 8; ++i) {
    float v = X[(size_t)w * cD + lane + i * 64];
    s += v; ss += v * v;
  }
#pragma unroll
  for (int o = 32; o >= 1; o >>= 1) { s += __shfl_xor(s, o); ss += __shfl_xor(ss, o); }
  if (lane == 0) {
    float m = s * (1.f / cD);
    M[w] = m;
    R[w] = rsqrtf(ss * (1.f / cD) - m * m + 1e-5f);
  }
}

// ======================= barrier-free per-batch scan ========================
// R9 = R8 with a 3-DEEP staging pipeline + bf16 A-buffers.
// R8 diagnosis: traffic clean (no spill, FETCH 114 MB) but dur unchanged vs
// R4 → the stall is L2 latency under 32-CU/XCD contention (each lockstep
// iteration needs 1 MB from each XCD L2 ≈ 585 cy BW + queueing latency).
// R8's 1-deep pipeline (vmcnt waits for loads issued ONE iteration ago)
// can't cover that. Changes: (1) 3 rotating buffers, stage kc+2 each iter,
// steady vmcnt(8) (x7: 10), tails 4/5→0; (2) drop per-iter lgkmcnt(0) —
// with 3 bufs the overwritten buffer's ds_reads completed 2 iterations ago
// (compiler-enforced before their MFMAs) → WAR-safe; (3) A-operands stored
// bf16 in LDS (R5/R6's passed pattern): f2bf at write, A-frag = one
// ds_read_b128, kills 2 ds_reads + 8 cvts per iter per wave.
struct Scan2Params {
  const float *item_seq, *init_state, *us_norm, *lnm, *lnr, *n1g, *n1b;
  const float *mcb1, *mcg, *mcbt, *mcb2, *ba, *be;
  const short *wt_m1, *wt_m2, *wt_k, *wt_v, *wt_ae, *q_all;
  float *mem_ctx;
};

__global__ __launch_bounds__(512, 2) void scan1s_k(Scan2Params p) {
  const int tid = threadIdx.x;
  const int lane = tid & 63, w = tid >> 6;     // wave 0..7 = head
  const int l15 = lane & 15, qd = lane >> 4;
  const int b = blockIdx.x;

  __shared__ short xcat_bf[1024]; // [us_norm | mem] as bf16 (A-operand)
  __shared__ float rbuf[512];
  __shared__ short x2bf[512];     // relu(LN(r)) as bf16 (A-operand)
  __shared__ float mo[1040];
  __shared__ short modbf[512];    // mod as bf16 (A-operand)
  __shared__ float kvb[1024];     // [k | v]
  __shared__ float khat[8][64];
  __shared__ float qh[8][64];
  __shared__ float aeta[8][2];    // [h][{alpha,eta}]
  __shared__ float st[2];         // meta-MLP LN {m, rstd}
  __shared__ float cb1[512], cg[512], cbt[512], cb2[1040];
  __shared__ float cn1g[512], cn1b[512], cba[8], cbe[8];
  // staging: 8 waves × 3 bufs × 4 slots × 512 shorts = 96 KB
  __shared__ short stg_flat[8 * 3 * 2048];
  // wave-7 extra tile (P4 alpha/eta cols, P6 Wa|We): 3 bufs × 1 KB
  __shared__ short x7e[3 * 512];

  auto stgp = [&](int buf) -> short* {
    unsigned idx = (unsigned)__builtin_amdgcn_readfirstlane((w * 3 + buf) * 2048);
    return &stg_flat[idx];
  };
  auto x7p = [&](int buf) -> short* {
    unsigned idx = (unsigned)__builtin_amdgcn_readfirstlane(buf * 512);
    return &x7e[idx];
  };

  // preload per-block constants + us_norm (512 threads)
  cb1[tid] = p.mcb1[tid]; cg[tid] = p.mcg[tid]; cbt[tid] = p.mcbt[tid];
  cn1g[tid] = p.n1g[tid]; cn1b[tid] = p.n1b[tid];
  cb2[tid] = p.mcb2[tid];
  cb2[512 + tid] = p.mcb2[512 + tid];
  if (tid < 16) cb2[1024 + tid] = p.mcb2[1024 + tid];   // alpha/eta bias slots
  if (tid < 8) { cba[tid] = p.ba[tid]; cbe[tid] = p.be[tid]; }
  xcat_bf[tid] = f2bf(p.us_norm[(size_t)b * cD + tid]);

  // load persistent state into registers (host input → non-temporal ok)
  float S[64];
  {
    const float* sp = p.init_state + ((((size_t)b) * cH + w) * cDH + lane) * cDH;
#pragma unroll
    for (int j = 0; j < 64; j += 4) {
      f32x4 t4 = __builtin_nontemporal_load((const f32x4*)(sp + j));
      S[j] = t4[0]; S[j + 1] = t4[1]; S[j + 2] = t4[2]; S[j + 3] = t4[3];
    }
  }
  float memv;
  {  // mem_ctx_0 = S . q̂_0
    float qv = bf2f(p.q_all[(size_t)b * cD + w * cDH + lane]);
    float qs = qv * qv;
#pragma unroll
    for (int o = 32; o >= 1; o >>= 1) qs += __shfl_xor(qs, o);
    qh[w][lane] = qv / fmaxf(sqrtf(qs), 1e-12f);
    memv = 0.f;
#pragma unroll
    for (int j = 0; j < 64; j += 4) {
      float4 q4 = *(const float4*)&qh[w][j];
      memv += S[j] * q4.x + S[j + 1] * q4.y + S[j + 2] * q4.z + S[j + 3] * q4.w;
    }
    xcat_bf[512 + w * cDH + lane] = f2bf(memv);
  }
  __syncthreads();

  for (int t = 0; t < cT; ++t) {
    // ---- P1: r = xcat @ mcW1 + b1 (32 kc; 4 tiles/wave; 3-deep dbuf) ----
    {
      f32x4 acc[4] = {};
#pragma unroll
      for (int g = 0; g < 2; ++g) {
        short* d = stgp(g);
#pragma unroll
        for (int i = 0; i < 4; ++i)
          stage_tile(p.wt_m1, (w * 4 + i) * 16, 1024, g * 32, d + i * 512, lane);
      }
      for (int kc = 0; kc < 32; ++kc) {
        if (kc + 2 < 32) {
          short* dn = stgp((kc + 2) % 3);
#pragma unroll
          for (int i = 0; i < 4; ++i)
            stage_tile(p.wt_m1, (w * 4 + i) * 16, 1024, (kc + 2) * 32, dn + i * 512, lane);
          asm volatile("s_waitcnt vmcnt(8)" ::: "memory");
        } else if (kc + 1 < 32) {
          asm volatile("s_waitcnt vmcnt(4)" ::: "memory");
        } else {
          asm volatile("s_waitcnt vmcnt(0)" ::: "memory");
        }
        bfrag A = {};
        if (l15 == 0) A = *(const bfrag*)(&xcat_bf[kc * 32 + qd * 8]);
        const short* bb = stgp(kc % 3);
#pragma unroll
        for (int i = 0; i < 4; ++i) {
          bfrag B = *(const bfrag*)(bb + i * 512 + lane * 8);
          acc[i] = __builtin_amdgcn_mfma_f32_16x16x32_bf16(A, B, acc[i], 0, 0, 0);
        }
      }
      if (lane < 16)
#pragma unroll
        for (int i = 0; i < 4; ++i) {
          int n0 = (w * 4 + i) * 16;
          rbuf[n0 + lane] = acc[i][0] + cb1[n0 + lane];
        }
    }
    __syncthreads();
    // ---- P2: LN stats of r (wave 0, R0's exact reduce pattern) ----
    if (w == 0) {
      float s = 0.f, ss = 0.f;
#pragma unroll
      for (int i = 0; i < 8; ++i) { float v = rbuf[lane + i * 64]; s += v; ss += v * v; }
#pragma unroll
      for (int o = 32; o >= 1; o >>= 1) { s += __shfl_xor(s, o); ss += __shfl_xor(ss, o); }
      if (lane == 0) {
        float m = s * (1.f / cD);
        st[0] = m;
        st[1] = rsqrtf(ss * (1.f / cD) - m * m + 1e-5f);
      }
    }
    __syncthreads();
    // ---- P3: x2 = relu(LN(r)) -> bf16 ----
    x2bf[tid] = f2bf(fmaxf((rbuf[tid] - st[0]) * st[1] * cg[tid] + cbt[tid], 0.f));
    __syncthreads();
    // ---- P4: mo = x2 @ mcW2 + b2 (2 halves × 16 kc; 3-deep; tile64 folded) -
    {
      f32x4 e = {};
#pragma unroll 1
      for (int hb = 0; hb < 2; ++hb) {
        f32x4 acc[4] = {};
        const bool x7 = (w == 7) && (hb == 0);
#pragma unroll
        for (int g = 0; g < 2; ++g) {
          short* d = stgp(g);
#pragma unroll
          for (int i = 0; i < 4; ++i)
            stage_tile(p.wt_m2, (hb * 32 + w * 4 + i) * 16, 512, g * 32, d + i * 512, lane);
          if (x7) stage_tile(p.wt_m2, 1024, 512, g * 32, x7p(g), lane);
        }
        for (int kc = 0; kc < 16; ++kc) {
          if (kc + 2 < 16) {
            short* dn = stgp((kc + 2) % 3);
#pragma unroll
            for (int i = 0; i < 4; ++i)
              stage_tile(p.wt_m2, (hb * 32 + w * 4 + i) * 16, 512, (kc + 2) * 32, dn + i * 512, lane);
            if (x7) {
              stage_tile(p.wt_m2, 1024, 512, (kc + 2) * 32, x7p((kc + 2) % 3), lane);
              asm volatile("s_waitcnt vmcnt(10)" ::: "memory");
            } else {
              asm volatile("s_waitcnt vmcnt(8)" ::: "memory");
            }
          } else if (kc + 1 < 16) {
            if (x7) asm volatile("s_waitcnt vmcnt(5)" ::: "memory");
            else    asm volatile("s_waitcnt vmcnt(4)" ::: "memory");
          } else {
            asm volatile("s_waitcnt vmcnt(0)" ::: "memory");
          }
          bfrag A = {};
          if (l15 == 0) A = *(const bfrag*)(&x2bf[kc * 32 + qd * 8]);
          const short* bb = stgp(kc % 3);
#pragma unroll
          for (int i = 0; i < 4; ++i) {
            bfrag B = *(const bfrag*)(bb + i * 512 + lane * 8);
            acc[i] = __builtin_amdgcn_mfma_f32_16x16x32_bf16(A, B, acc[i], 0, 0, 0);
          }
          if (x7) {
            bfrag B = *(const bfrag*)(x7p(kc % 3) + lane * 8);
            e = __builtin_amdgcn_mfma_f32_16x16x32_bf16(A, B, e, 0, 0, 0);
          }
        }
        if (lane < 16)
#pragma unroll
          for (int i = 0; i < 4; ++i) {
            int n0 = (hb * 32 + w * 4 + i) * 16;
            mo[n0 + lane] = acc[i][0] + cb2[n0 + lane];
          }
      }
      if (w == 7 && lane < 16) mo[1024 + lane] = e[0] + cb2[1024 + lane];
    }
    __syncthreads();
    // ---- P5: mod = i_norm*(1+tanh(gamma)) + beta -> bf16 ----
    {
      float m2 = p.lnm[(size_t)t * cB + b];
      float r2 = p.lnr[(size_t)t * cB + b];
      float iv = __builtin_nontemporal_load(
          p.item_seq + (((size_t)b) * cT + t) * cD + tid);
      float inm = (iv - m2) * r2 * cn1g[tid] + cn1b[tid];
      modbf[tid] = f2bf(inm * (1.f + tanhf(mo[tid])) + mo[512 + tid]);
    }
    __syncthreads();
    // ---- P6: [k|v] = mod @ [Wk|Wv] (2 halves × 16 kc; 3-deep; ae folded) ---
    {
      f32x4 e = {};
#pragma unroll 1
      for (int hb = 0; hb < 2; ++hb) {
        const short* wt = hb ? p.wt_v : p.wt_k;
        const int base = hb ? 512 : 0;
        const bool x7 = (w == 7) && (hb == 0);
        f32x4 acc[4] = {};
#pragma unroll
        for (int g = 0; g < 2; ++g) {
          short* d = stgp(g);
#pragma unroll
          for (int i = 0; i < 4; ++i)
            stage_tile(wt, (w * 4 + i) * 16, 512, g * 32, d + i * 512, lane);
          if (x7) stage_tile(p.wt_ae, 0, 512, g * 32, x7p(g), lane);
        }
        for (int kc = 0; kc < 16; ++kc) {
          if (kc + 2 < 16) {
            short* dn = stgp((kc + 2) % 3);
#pragma unroll
            for (int i = 0; i < 4; ++i)
              stage_tile(wt, (w * 4 + i) * 16, 512, (kc + 2) * 32, dn + i * 512, lane);
            if (x7) {
              stage_tile(p.wt_ae, 0, 512, (kc + 2) * 32, x7p((kc + 2) % 3), lane);
              asm volatile("s_waitcnt vmcnt(10)" ::: "memory");
            } else {
              asm volatile("s_waitcnt vmcnt(8)" ::: "memory");
            }
          } else if (kc + 1 < 16) {
            if (x7) asm volatile("s_waitcnt vmcnt(5)" ::: "memory");
            else    asm volatile("s_waitcnt vmcnt(4)" ::: "memory");
          } else {
            asm volatile("s_waitcnt vmcnt(0)" ::: "memory");
          }
          bfrag A = {};
          if (l15 == 0) A = *(const bfrag*)(&modbf[kc * 32 + qd * 8]);
          const short* bb = stgp(kc % 3);
#pragma unroll
          for (int i = 0; i < 4; ++i) {
            bfrag B = *(const bfrag*)(bb + i * 512 + lane * 8);
            acc[i] = __builtin_amdgcn_mfma_f32_16x16x32_bf16(A, B, acc[i], 0, 0, 0);
          }
          if (x7) {
            bfrag B = *(const bfrag*)(x7p(kc % 3) + lane * 8);
            e = __builtin_amdgcn_mfma_f32_16x16x32_bf16(A, B, e, 0, 0, 0);
          }
        }
        if (lane < 16)
#pragma unroll
          for (int i = 0; i < 4; ++i) {
            int n0 = (w * 4 + i) * 16;
            kvb[base + n0 + lane] = acc[i][0];
          }
      }
      if (w == 7 && lane < 16) {
        if (lane < 8) {
          aeta[lane][0] = sigm(e[0] + cba[lane] + mo[1024 + lane]);
        } else {
          int hh = lane - 8;
          aeta[hh][1] = cSCALE * sigm(e[0] + cbe[hh] + mo[1032 + hh]);
        }
      }
    }
    __syncthreads();
    // ---- P7: state update (registers) + mem with q_{t+1} ----
    {
      float kvv = kvb[w * cDH + lane];
      float ks = kvv * kvv;
#pragma unroll
      for (int o = 32; o >= 1; o >>= 1) ks += __shfl_xor(ks, o);
      khat[w][lane] = kvv / fmaxf(sqrtf(ks), 1e-12f);
      float qv = bf2f(p.q_all[((size_t)(t + 1) * cB + b) * cD + w * cDH + lane]);
      float qs = qv * qv;
#pragma unroll
      for (int o = 32; o >= 1; o >>= 1) qs += __shfl_xor(qs, o);
      qh[w][lane] = qv / fmaxf(sqrtf(qs), 1e-12f);

      float vv = kvb[512 + w * cDH + lane];
      float al = aeta[w][0], et = aeta[w][1];
      float pred = 0.f;
#pragma unroll
      for (int j = 0; j < 64; j += 4) {
        float4 k4 = *(const float4*)&khat[w][j];
        pred += S[j] * k4.x + S[j + 1] * k4.y + S[j + 2] * k4.z + S[j + 3] * k4.w;
      }
      float f = et * (vv - pred), oma = 1.f - al;
      memv = 0.f;
#pragma unroll
      for (int j = 0; j < 64; j += 4) {
        float4 k4 = *(const float4*)&khat[w][j];
        float4 q4 = *(const float4*)&qh[w][j];
        S[j]     = oma * S[j]     + f * k4.x; memv += S[j]     * q4.x;
        S[j + 1] = oma * S[j + 1] + f * k4.y; memv += S[j + 1] * q4.y;
        S[j + 2] = oma * S[j + 2] + f * k4.z; memv += S[j + 2] * q4.z;
        S[j + 3] = oma * S[j + 3] + f * k4.w; memv += S[j + 3] * q4.w;
      }
      xcat_bf[512 + w * cDH + lane] = f2bf(memv);
    }
    __syncthreads();
  }

  // final memory read (slot 64 = last-item query) is in memv
  p.mem_ctx[(size_t)b * cD + w * cDH + lane] = memv;
}

// ======================= host launch ========================================
extern "C" void kernel_launch(void* const* d_in, const int* in_sizes, int n_in,
                              void* d_out, int out_size, void* d_ws, size_t ws_size,
                              hipStream_t stream) {
  (void)in_sizes; (void)n_in; (void)out_size;
  const float* item_seq   = (const float*)d_in[0];
  const float* user_stat  = (const float*)d_in[1];
  const float* last_item  = (const float*)d_in[2];
  const float* init_state = (const float*)d_in[3];
  const float* Wq  = (const float*)d_in[4];
  const float* Wk  = (const float*)d_in[5];
  const float* Wv  = (const float*)d_in[6];
  const float* Wa  = (const float*)d_in[7];
  const float* ba  = (const float*)d_in[8];
  const float* We  = (const float*)d_in[9];
  const float* be  = (const float*)d_in[10];
  const float* mcW1 = (const float*)d_in[11];
  const float* mcb1 = (const float*)d_in[12];
  const float* mcg  = (const float*)d_in[13];
  const float* mcbt = (const float*)d_in[14];
  const float* mcW2 = (const float*)d_in[15];
  const float* mcb2 = (const float*)d_in[16];
  const float* Wo  = (const float*)d_in[17];
  const float* bo  = (const float*)d_in[18];
  const float* W1  = (const float*)d_in[19];
  const float* b1  = (const float*)d_in[20];
  const float* W2  = (const float*)d_in[21];
  const float* b2  = (const float*)d_in[22];
  const float* n1g = (const float*)d_in[23];
  const float* n1b = (const float*)d_in[24];
  const float* n2g = (const float*)d_in[25];
  const float* n2b = (const float*)d_in[26];

  float* ws = (float*)d_ws;
  size_t off = 0;
  auto alloc = [&](size_t n) { float* p = ws + off; off += n; return p; };
  auto salloc = [&](size_t n) { return (short*)alloc((n + 1) / 2); };

  short* q_all   = salloc((size_t)(cT + 1) * cB * cD);
  float* lnm     = alloc((size_t)(cT + 1) * cB);
  float* lnr     = alloc((size_t)(cT + 1) * cB);
  float* us_norm = alloc((size_t)cB * cD);
  float* mem_ctx = alloc((size_t)cB * cD);
  float* x_buf   = alloc((size_t)cB * cD);
  float* xm      = alloc(cB);
  float* xr      = alloc(cB);
  float* u_buf   = alloc((size_t)cB * cFF);
  short* wt_q    = salloc((size_t)512 * 512);
  short* wt_m1   = salloc((size_t)512 * 1024);
  short* wt_m2   = salloc((size_t)1040 * 512);
  short* wt_k    = salloc((size_t)512 * 512);
  short* wt_v    = salloc((size_t)512 * 512);
  short* wt_ae   = salloc((size_t)16 * 512);
  short* wt_o    = salloc((size_t)512 * 512);
  short* wt_o_l  = salloc((size_t)512 * 512);
  short* wt_1    = salloc((size_t)2048 * 512);
  short* wt_1_l  = salloc((size_t)2048 * 512);
  short* wt_2    = salloc((size_t)512 * 2048);
  short* wt_2_l  = salloc((size_t)512 * 2048);
  if (ws_size < off * sizeof(float)) return;

  // --- prep: bf16 transposed weights ---
  tconv<<<dim3(16, 16), 256, 0, stream>>>(Wq, wt_q, 512, 512);
  tconv<<<dim3(32, 16), 256, 0, stream>>>(mcW1, wt_m1, 1024, 512);
  tconv<<<dim3(16, 33), 256, 0, stream>>>(mcW2, wt_m2, 512, 1040);
  tconv<<<dim3(16, 16), 256, 0, stream>>>(Wk, wt_k, 512, 512);
  tconv<<<dim3(16, 16), 256, 0, stream>>>(Wv, wt_v, 512, 512);
  tconv<<<dim3(16, 1), 256, 0, stream>>>(Wa, wt_ae, 512, 8);
  tconv<<<dim3(16, 1), 256, 0, stream>>>(We, wt_ae + (size_t)8 * 512, 512, 8);
  tconv2<<<dim3(16, 16), 256, 0, stream>>>(Wo, wt_o, wt_o_l, 512, 512);
  tconv2<<<dim3(16, 64), 256, 0, stream>>>(W1, wt_1, wt_1_l, 512, 2048);
  tconv2<<<dim3(64, 16), 256, 0, stream>>>(W2, wt_2, wt_2_l, 2048, 512);

  ln_stats_k<<<(cT * cB + 2 * cB) / 4, 256, 0, stream>>>(
      item_seq, last_item, user_stat, n1g, n1b, lnm, lnr, us_norm);

  {  // q_all for all 65 slots (bf16 out)
    GemmArgs p{}; p.A = item_seq; p.A2 = last_item; p.sm = lnm; p.sr = lnr;
    p.g = n1g; p.b = n1b; p.WT = wt_q; p.Os = q_all;
    mgemm<MQ, 512><<<dim3(520, 8), 256, 0, stream>>>(p, 512);
  }

  {  // --- barrier-free scan: one block per batch row, 3-deep staged weights -
    Scan2Params sp{};
    sp.item_seq = item_seq; sp.init_state = init_state; sp.us_norm = us_norm;
    sp.lnm = lnm; sp.lnr = lnr; sp.n1g = n1g; sp.n1b = n1b;
    sp.mcb1 = mcb1; sp.mcg = mcg; sp.mcbt = mcbt; sp.mcb2 = mcb2;
    sp.ba = ba; sp.be = be;
    sp.wt_m1 = wt_m1; sp.wt_m2 = wt_m2; sp.wt_k = wt_k; sp.wt_v = wt_v;
    sp.wt_ae = wt_ae; sp.q_all = q_all;
    sp.mem_ctx = mem_ctx;
    scan1s_k<<<dim3(cB), dim3(512), 0, stream>>>(sp);
  }

  {  // x = user + mem_ctx @ Wo + bo  (split precision)
    GemmArgs p{}; p.A = mem_ctx; p.WT = wt_o; p.WT2 = wt_o_l;
    p.bias = bo; p.extra = user_stat; p.O = x_buf;
    pgemm<MWO, 512><<<dim3(8, 8), 256, 0, stream>>>(p, 512);
  }
  row_stats_k<<<cB / 4, 256, 0, stream>>>(x_buf, xm, xr);
  {  // u = relu(LN(x) @ W1 + b1)  (split precision)
    GemmArgs p{}; p.A = x_buf; p.sm = xm; p.sr = xr; p.g = n2g; p.b = n2b;
    p.WT = wt_1; p.WT2 = wt_1_l; p.bias = b1; p.O = u_buf;
    pgemm<MFF1, 512><<<dim3(8, 32), 256, 0, stream>>>(p, 512);
  }
  {  // out = x + u @ W2 + b2  (split precision)
    GemmArgs p{}; p.A = u_buf; p.WT = wt_2; p.WT2 = wt_2_l;
    p.bias = b2; p.extra = x_buf; p.O = (float*)d_out;
    pgemm<MFF2, 2048><<<dim3(8, 8), 256, 0, stream>>>(p, 2048);
  }
}

// Round 10
// 5755.896 us; speedup vs baseline: 2.1107x; 2.1107x over previous
//
#include <hip/hip_runtime.h>
#include <cmath>

constexpr int cB = 512, cT = 64, cD = 512, cH = 8, cDH = 64, cFF = 2048;
constexpr float cSCALE = 0.125f;  // DH^-0.5

typedef short bfrag __attribute__((ext_vector_type(8)));   // 8 bf16 = 4 VGPRs
typedef float f32x4 __attribute__((ext_vector_type(4)));

__device__ __forceinline__ short f2bf(float x) {
  union { float f; unsigned u; } v{x};
  unsigned r = v.u + 0x7fff + ((v.u >> 16) & 1);
  return (short)(r >> 16);
}
__device__ __forceinline__ float bf2f(short s) {
  union { unsigned u; float f; } v;
  v.u = ((unsigned)(unsigned short)s) << 16;
  return v.f;
}
__device__ __forceinline__ float sigm(float z) { return 1.f / (1.f + __expf(-z)); }

// async global->LDS from PACKED weights: fully coalesced, lane l reads 16B at
// pk + slot*1KB + l*16, lands at dst + l*16. (R10: replaces the 16-row
// scattered gather that capped every prior variant at ~2270 cy/iter.)
__device__ __forceinline__ void stage_pk(const short* pk, int slot,
                                         short* dst, int lane) {
  const short* src = pk + (size_t)slot * 512 + lane * 8;
  __builtin_amdgcn_global_load_lds(
      (const __attribute__((address_space(1))) void*)src,
      (__attribute__((address_space(3))) void*)dst, 16, 0, 0);
}

// ======================= standalone GEMMs (prep / epilogue) =================
enum GemmMode { MQ = 0, MWO, MFF1, MFF2 };

struct GemmArgs {
  const float *A, *A2, *sm, *sr, *g, *b;
  const short *WT, *WT2;   // hi / lo
  const float *bias, *extra;
  float *O;
  short *Os;
};

template<int MODE>
__device__ __forceinline__ float loadA(const GemmArgs& p, int r, int k) {
  if constexpr (MODE == MQ) {
    int t = r >> 9, bb = r & 511;
    float v = (t < cT) ? p.A[((size_t)bb * cT + t) * cD + k]
                       : p.A2[(size_t)bb * cD + k];
    return (v - p.sm[r]) * p.sr[r] * p.g[k] + p.b[k];
  } else if constexpr (MODE == MFF1) {
    return (p.A[(size_t)r * cD + k] - p.sm[r]) * p.sr[r] * p.g[k] + p.b[k];
  } else if constexpr (MODE == MFF2) {
    return p.A[(size_t)r * cFF + k];
  } else {  // MWO
    return p.A[(size_t)r * cD + k];
  }
}

template<int MODE>
__device__ __forceinline__ void epi(const GemmArgs& p, int r, int cn, float acc) {
  if constexpr (MODE == MQ) {
    p.Os[(size_t)r * cD + cn] = f2bf(acc);  // raw q, bf16 (l2n at consumer)
  } else if constexpr (MODE == MWO) {
    p.O[(size_t)r * cD + cn] = p.extra[(size_t)r * cD + cn] + acc + p.bias[cn];
  } else if constexpr (MODE == MFF1) {
    p.O[(size_t)r * cFF + cn] = fmaxf(acc + p.bias[cn], 0.f);
  } else {  // MFF2
    p.O[(size_t)r * cD + cn] = p.extra[(size_t)r * cD + cn] + acc + p.bias[cn];
  }
}

// single-precision bf16 MFMA GEMM (q_all)
template<int MODE, int LDW>
__global__ __launch_bounds__(256) void mgemm(GemmArgs p, int K) {
  __shared__ short As[64][32];
  __shared__ short Bs[64][32];
  const int tid = threadIdx.x;
  const int lane = tid & 63, wid = tid >> 6;
  const int wm = wid & 1, wn = wid >> 1;
  const int l15 = lane & 15, qd = lane >> 4;
  const int row0 = blockIdx.x * 64;
  const int n0 = blockIdx.y * 64;

  f32x4 acc[2][2] = {};
  const int sm = tid >> 2;
  const int sk = (tid & 3) * 8;

  for (int k0 = 0; k0 < K; k0 += 32) {
    {
      short tmp[8];
#pragma unroll
      for (int j = 0; j < 8; ++j)
        tmp[j] = f2bf(loadA<MODE>(p, row0 + sm, k0 + sk + j));
      *((bfrag*)&As[sm][0] + (sk >> 3)) = *(bfrag*)tmp;
    }
    *((bfrag*)&Bs[sm][0] + (sk >> 3)) =
        *(const bfrag*)(p.WT + (size_t)(n0 + sm) * LDW + k0 + sk);
    __syncthreads();
    bfrag a0 = *((bfrag*)&As[wm * 32 + l15][0] + qd);
    bfrag a1 = *((bfrag*)&As[wm * 32 + 16 + l15][0] + qd);
    bfrag b0 = *((bfrag*)&Bs[wn * 32 + l15][0] + qd);
    bfrag b1 = *((bfrag*)&Bs[wn * 32 + 16 + l15][0] + qd);
    acc[0][0] = __builtin_amdgcn_mfma_f32_16x16x32_bf16(a0, b0, acc[0][0], 0, 0, 0);
    acc[0][1] = __builtin_amdgcn_mfma_f32_16x16x32_bf16(a0, b1, acc[0][1], 0, 0, 0);
    acc[1][0] = __builtin_amdgcn_mfma_f32_16x16x32_bf16(a1, b0, acc[1][0], 0, 0, 0);
    acc[1][1] = __builtin_amdgcn_mfma_f32_16x16x32_bf16(a1, b1, acc[1][1], 0, 0, 0);
    __syncthreads();
  }

#pragma unroll
  for (int fm = 0; fm < 2; ++fm)
#pragma unroll
    for (int fn = 0; fn < 2; ++fn)
#pragma unroll
      for (int rg = 0; rg < 4; ++rg)
        epi<MODE>(p, row0 + wm * 32 + fm * 16 + qd * 4 + rg,
                  n0 + wn * 32 + fn * 16 + l15, acc[fm][fn][rg]);
}

// split-precision GEMM (post-scan layers)
template<int MODE, int LDW>
__global__ __launch_bounds__(256) void pgemm(GemmArgs p, int K) {
  __shared__ short Ah[64][32], Al[64][32];
  __shared__ short Bh[64][32], Bl[64][32];
  const int tid = threadIdx.x;
  const int lane = tid & 63, wid = tid >> 6;
  const int wm = wid & 1, wn = wid >> 1;
  const int l15 = lane & 15, qd = lane >> 4;
  const int row0 = blockIdx.x * 64;
  const int n0 = blockIdx.y * 64;

  f32x4 acc[2][2] = {};
  const int sm = tid >> 2;
  const int sk = (tid & 3) * 8;

  for (int k0 = 0; k0 < K; k0 += 32) {
    {
      short th[8], tl[8];
#pragma unroll
      for (int j = 0; j < 8; ++j) {
        float a = loadA<MODE>(p, row0 + sm, k0 + sk + j);
        short h = f2bf(a);
        th[j] = h;
        tl[j] = f2bf(a - bf2f(h));
      }
      *((bfrag*)&Ah[sm][0] + (sk >> 3)) = *(bfrag*)th;
      *((bfrag*)&Al[sm][0] + (sk >> 3)) = *(bfrag*)tl;
    }
    *((bfrag*)&Bh[sm][0] + (sk >> 3)) =
        *(const bfrag*)(p.WT + (size_t)(n0 + sm) * LDW + k0 + sk);
    *((bfrag*)&Bl[sm][0] + (sk >> 3)) =
        *(const bfrag*)(p.WT2 + (size_t)(n0 + sm) * LDW + k0 + sk);
    __syncthreads();
#pragma unroll
    for (int fm = 0; fm < 2; ++fm) {
      bfrag ah = *((bfrag*)&Ah[wm * 32 + fm * 16 + l15][0] + qd);
      bfrag al = *((bfrag*)&Al[wm * 32 + fm * 16 + l15][0] + qd);
#pragma unroll
      for (int fn = 0; fn < 2; ++fn) {
        bfrag bh = *((bfrag*)&Bh[wn * 32 + fn * 16 + l15][0] + qd);
        bfrag bl = *((bfrag*)&Bl[wn * 32 + fn * 16 + l15][0] + qd);
        acc[fm][fn] = __builtin_amdgcn_mfma_f32_16x16x32_bf16(al, bh, acc[fm][fn], 0, 0, 0);
        acc[fm][fn] = __builtin_amdgcn_mfma_f32_16x16x32_bf16(ah, bl, acc[fm][fn], 0, 0, 0);
        acc[fm][fn] = __builtin_amdgcn_mfma_f32_16x16x32_bf16(ah, bh, acc[fm][fn], 0, 0, 0);
      }
    }
    __syncthreads();
  }

#pragma unroll
  for (int fm = 0; fm < 2; ++fm)
#pragma unroll
    for (int fn = 0; fn < 2; ++fn)
#pragma unroll
      for (int rg = 0; rg < 4; ++rg)
        epi<MODE>(p, row0 + wm * 32 + fm * 16 + qd * 4 + rg,
                  n0 + wn * 32 + fn * 16 + l15, acc[fm][fn][rg]);
}

// ======================= weight transpose + bf16 ============================
__global__ __launch_bounds__(256) void tconv(const float* __restrict__ W,
                                             short* __restrict__ WT, int K, int N) {
  __shared__ float tile[32][33];
  int k0 = blockIdx.x * 32, n0 = blockIdx.y * 32;
  int tx = threadIdx.x & 31, ty = threadIdx.x >> 5;
#pragma unroll
  for (int j = 0; j < 32; j += 8) {
    int k = k0 + ty + j, n = n0 + tx;
    tile[ty + j][tx] = (k < K && n < N) ? W[(size_t)k * N + n] : 0.f;
  }
  __syncthreads();
#pragma unroll
  for (int j = 0; j < 32; j += 8) {
    int n = n0 + ty + j, k = k0 + tx;
    if (n < N && k < K) WT[(size_t)n * K + k] = f2bf(tile[tx][ty + j]);
  }
}

__global__ __launch_bounds__(256) void tconv2(const float* __restrict__ W,
                                              short* __restrict__ WTh,
                                              short* __restrict__ WTl, int K, int N) {
  __shared__ float tile[32][33];
  int k0 = blockIdx.x * 32, n0 = blockIdx.y * 32;
  int tx = threadIdx.x & 31, ty = threadIdx.x >> 5;
#pragma unroll
  for (int j = 0; j < 32; j += 8) {
    int k = k0 + ty + j, n = n0 + tx;
    tile[ty + j][tx] = (k < K && n < N) ? W[(size_t)k * N + n] : 0.f;
  }
  __syncthreads();
#pragma unroll
  for (int j = 0; j < 32; j += 8) {
    int n = n0 + ty + j, k = k0 + tx;
    if (n < N && k < K) {
      float v = tile[tx][ty + j];
      short h = f2bf(v);
      WTh[(size_t)n * K + k] = h;
      WTl[(size_t)n * K + k] = f2bf(v - bf2f(h));
    }
  }
}

// ======================= weight packer (scan consumption order) =============
// pk[(kc*NTILE + tn)*512 + lane*8 + e] =
//   wt[(base_n + tn*16 + (lane&15))*ldw + kc*32 + (lane>>4)*8 + e]
// Pure permutation of the bf16 values → scan math is bit-identical.
__global__ __launch_bounds__(256) void packw(const short* __restrict__ wt,
                                             short* __restrict__ pk,
                                             int ldw, int KC, int NTILE,
                                             int base_n) {
  int idx = blockIdx.x * 4 + (threadIdx.x >> 6);
  if (idx >= KC * NTILE) return;
  int lane = threadIdx.x & 63;
  int kc = idx / NTILE, tn = idx % NTILE;
  const short* src = wt + (size_t)(base_n + tn * 16 + (lane & 15)) * ldw +
                     kc * 32 + (lane >> 4) * 8;
  *(bfrag*)(pk + (size_t)idx * 512 + lane * 8) = *(const bfrag*)src;
}

// ======================= LN stats + us_norm =================================
__global__ __launch_bounds__(256) void ln_stats_k(
    const float* __restrict__ item_seq, const float* __restrict__ last_item,
    const float* __restrict__ user, const float* __restrict__ n1g,
    const float* __restrict__ n1b, float* __restrict__ lnm,
    float* __restrict__ lnr, float* __restrict__ us_norm) {
  const int lane = threadIdx.x & 63;
  const int w = blockIdx.x * 4 + (threadIdx.x >> 6);
  const float* src;
  int cls, bi = 0;
  if (w < cT * cB) {
    int t = w >> 9, bb = w & 511;
    src = item_seq + ((size_t)bb * cT + t) * cD;
    cls = 0;
  } else if (w < cT * cB + cB) {
    bi = w - cT * cB;
    src = last_item + (size_t)bi * cD;
    cls = 1;
  } else {
    bi = w - cT * cB - cB;
    src = user + (size_t)bi * cD;
    cls = 2;
  }
  float x[8], s = 0.f, ss = 0.f;
#pragma unroll
  for (int i = 0; i < 8; ++i) {
    float v = src[lane + i * 64];
    x[i] = v; s += v; ss += v * v;
  }
#pragma unroll
  for (int o = 32; o >= 1; o >>= 1) { s += __shfl_xor(s, o); ss += __shfl_xor(ss, o); }
  float m = s * (1.f / cD);
  float rstd = rsqrtf(ss * (1.f / cD) - m * m + 1e-5f);
  if (cls == 0) {
    if (lane == 0) { lnm[w] = m; lnr[w] = rstd; }
  } else if (cls == 1) {
    if (lane == 0) { lnm[cT * cB + bi] = m; lnr[cT * cB + bi] = rstd; }
  } else {
#pragma unroll
    for (int i = 0; i < 8; ++i) {
      int d = lane + i * 64;
      us_norm[(size_t)bi * cD + d] = (x[i] - m) * rstd * n1g[d] + n1b[d];
    }
  }
}

// ======================= per-row stats ======================================
__global__ __launch_bounds__(256) void row_stats_k(const float* __restrict__ X,
                                                   float* __restrict__ M,
                                                   float* __restrict__ R) {
  const int lane = threadIdx.x & 63;
  const int w = blockIdx.x * 4 + (threadIdx.x >> 6);
  float s = 0.f, ss = 0.f;
#pragma unroll
  for (int i = 0; i < 8; ++i) {
    float v = X[(size_t)w * cD + lane + i * 64];
    s += v; ss += v * v;
  }
#pragma unroll
  for (int o = 32; o >= 1; o >>= 1) { s += __shfl_xor(s, o); ss += __shfl_xor(ss, o); }
  if (lane == 0) {
    float m = s * (1.f / cD);
    M[w] = m;
    R[w] = rsqrtf(ss * (1.f / cD) - m * m + 1e-5f);
  }
}

// ======================= barrier-free per-batch scan ========================
// R10 = R9 structure with PACKED weight staging. The invariant ~90 µs/step
// across R0/R4/R8/R9 (spill vs none, direct vs staged, 1- vs 2-deep, L2 vs
// HBM source) pointed at the load pattern itself: each stage_tile was a
// 16-row scatter = 16 distinct 64-B lines per instruction (~2270 cy/iter of
// line-gather throughput). packw pre-permutes weights into [kc][wave][tile]
// consumption order so each wave's 4 KB/iter is contiguous and each
// global_load_lds is the canonical coalesced lane*16B pattern (m97-proven).
// Same bf16 bits → bit-identical math to R9 (passed).
struct Scan2Params {
  const float *item_seq, *init_state, *us_norm, *lnm, *lnr, *n1g, *n1b;
  const float *mcb1, *mcg, *mcbt, *mcb2, *ba, *be;
  const short *pk_m1, *pk_m2, *pk_m2x, *pk_k, *pk_v, *pk_ae, *q_all;
  float *mem_ctx;
};

__global__ __launch_bounds__(512, 2) void scan1s_k(Scan2Params p) {
  const int tid = threadIdx.x;
  const int lane = tid & 63, w = tid >> 6;     // wave 0..7 = head
  const int l15 = lane & 15, qd = lane >> 4;
  const int b = blockIdx.x;

  __shared__ short xcat_bf[1024]; // [us_norm | mem] as bf16 (A-operand)
  __shared__ float rbuf[512];
  __shared__ short x2bf[512];     // relu(LN(r)) as bf16 (A-operand)
  __shared__ float mo[1040];
  __shared__ short modbf[512];    // mod as bf16 (A-operand)
  __shared__ float kvb[1024];     // [k | v]
  __shared__ float khat[8][64];
  __shared__ float qh[8][64];
  __shared__ float aeta[8][2];    // [h][{alpha,eta}]
  __shared__ float st[2];         // meta-MLP LN {m, rstd}
  __shared__ float cb1[512], cg[512], cbt[512], cb2[1040];
  __shared__ float cn1g[512], cn1b[512], cba[8], cbe[8];
  // staging: 8 waves × 3 bufs × 4 slots × 512 shorts = 96 KB
  __shared__ short stg_flat[8 * 3 * 2048];
  // wave-7 extra tile (P4 alpha/eta cols, P6 Wa|We): 3 bufs × 1 KB
  __shared__ short x7e[3 * 512];

  auto stgp = [&](int buf) -> short* {
    unsigned idx = (unsigned)__builtin_amdgcn_readfirstlane((w * 3 + buf) * 2048);
    return &stg_flat[idx];
  };
  auto x7p = [&](int buf) -> short* {
    unsigned idx = (unsigned)__builtin_amdgcn_readfirstlane(buf * 512);
    return &x7e[idx];
  };

  // preload per-block constants + us_norm (512 threads)
  cb1[tid] = p.mcb1[tid]; cg[tid] = p.mcg[tid]; cbt[tid] = p.mcbt[tid];
  cn1g[tid] = p.n1g[tid]; cn1b[tid] = p.n1b[tid];
  cb2[tid] = p.mcb2[tid];
  cb2[512 + tid] = p.mcb2[512 + tid];
  if (tid < 16) cb2[1024 + tid] = p.mcb2[1024 + tid];   // alpha/eta bias slots
  if (tid < 8) { cba[tid] = p.ba[tid]; cbe[tid] = p.be[tid]; }
  xcat_bf[tid] = f2bf(p.us_norm[(size_t)b * cD + tid]);

  // load persistent state into registers (host input → non-temporal ok)
  float S[64];
  {
    const float* sp = p.init_state + ((((size_t)b) * cH + w) * cDH + lane) * cDH;
#pragma unroll
    for (int j = 0; j < 64; j += 4) {
      f32x4 t4 = __builtin_nontemporal_load((const f32x4*)(sp + j));
      S[j] = t4[0]; S[j + 1] = t4[1]; S[j + 2] = t4[2]; S[j + 3] = t4[3];
    }
  }
  float memv;
  {  // mem_ctx_0 = S . q̂_0
    float qv = bf2f(p.q_all[(size_t)b * cD + w * cDH + lane]);
    float qs = qv * qv;
#pragma unroll
    for (int o = 32; o >= 1; o >>= 1) qs += __shfl_xor(qs, o);
    qh[w][lane] = qv / fmaxf(sqrtf(qs), 1e-12f);
    memv = 0.f;
#pragma unroll
    for (int j = 0; j < 64; j += 4) {
      float4 q4 = *(const float4*)&qh[w][j];
      memv += S[j] * q4.x + S[j + 1] * q4.y + S[j + 2] * q4.z + S[j + 3] * q4.w;
    }
    xcat_bf[512 + w * cDH + lane] = f2bf(memv);
  }
  __syncthreads();

  for (int t = 0; t < cT; ++t) {
    // ---- P1: r = xcat @ mcW1 + b1 (32 kc; 4 tiles/wave; 3-deep dbuf) ----
    {
      f32x4 acc[4] = {};
#pragma unroll
      for (int g = 0; g < 2; ++g) {
        short* d = stgp(g);
#pragma unroll
        for (int i = 0; i < 4; ++i)
          stage_pk(p.pk_m1, g * 32 + w * 4 + i, d + i * 512, lane);
      }
      for (int kc = 0; kc < 32; ++kc) {
        if (kc + 2 < 32) {
          short* dn = stgp((kc + 2) % 3);
#pragma unroll
          for (int i = 0; i < 4; ++i)
            stage_pk(p.pk_m1, (kc + 2) * 32 + w * 4 + i, dn + i * 512, lane);
          asm volatile("s_waitcnt vmcnt(8)" ::: "memory");
        } else if (kc + 1 < 32) {
          asm volatile("s_waitcnt vmcnt(4)" ::: "memory");
        } else {
          asm volatile("s_waitcnt vmcnt(0)" ::: "memory");
        }
        bfrag A = {};
        if (l15 == 0) A = *(const bfrag*)(&xcat_bf[kc * 32 + qd * 8]);
        const short* bb = stgp(kc % 3);
#pragma unroll
        for (int i = 0; i < 4; ++i) {
          bfrag B = *(const bfrag*)(bb + i * 512 + lane * 8);
          acc[i] = __builtin_amdgcn_mfma_f32_16x16x32_bf16(A, B, acc[i], 0, 0, 0);
        }
      }
      if (lane < 16)
#pragma unroll
        for (int i = 0; i < 4; ++i) {
          int n0 = (w * 4 + i) * 16;
          rbuf[n0 + lane] = acc[i][0] + cb1[n0 + lane];
        }
    }
    __syncthreads();
    // ---- P2: LN stats of r (wave 0, R0's exact reduce pattern) ----
    if (w == 0) {
      float s = 0.f, ss = 0.f;
#pragma unroll
      for (int i = 0; i < 8; ++i) { float v = rbuf[lane + i * 64]; s += v; ss += v * v; }
#pragma unroll
      for (int o = 32; o >= 1; o >>= 1) { s += __shfl_xor(s, o); ss += __shfl_xor(ss, o); }
      if (lane == 0) {
        float m = s * (1.f / cD);
        st[0] = m;
        st[1] = rsqrtf(ss * (1.f / cD) - m * m + 1e-5f);
      }
    }
    __syncthreads();
    // ---- P3: x2 = relu(LN(r)) -> bf16 ----
    x2bf[tid] = f2bf(fmaxf((rbuf[tid] - st[0]) * st[1] * cg[tid] + cbt[tid], 0.f));
    __syncthreads();
    // ---- P4: mo = x2 @ mcW2 + b2 (2 halves × 16 kc; 3-deep; tile64 folded) -
    {
      f32x4 e = {};
#pragma unroll 1
      for (int hb = 0; hb < 2; ++hb) {
        const short* pk = p.pk_m2 + (size_t)hb * (16 * 32 * 512);
        f32x4 acc[4] = {};
        const bool x7 = (w == 7) && (hb == 0);
#pragma unroll
        for (int g = 0; g < 2; ++g) {
          short* d = stgp(g);
#pragma unroll
          for (int i = 0; i < 4; ++i)
            stage_pk(pk, g * 32 + w * 4 + i, d + i * 512, lane);
          if (x7) stage_pk(p.pk_m2x, g, x7p(g), lane);
        }
        for (int kc = 0; kc < 16; ++kc) {
          if (kc + 2 < 16) {
            short* dn = stgp((kc + 2) % 3);
#pragma unroll
            for (int i = 0; i < 4; ++i)
              stage_pk(pk, (kc + 2) * 32 + w * 4 + i, dn + i * 512, lane);
            if (x7) {
              stage_pk(p.pk_m2x, kc + 2, x7p((kc + 2) % 3), lane);
              asm volatile("s_waitcnt vmcnt(10)" ::: "memory");
            } else {
              asm volatile("s_waitcnt vmcnt(8)" ::: "memory");
            }
          } else if (kc + 1 < 16) {
            if (x7) asm volatile("s_waitcnt vmcnt(5)" ::: "memory");
            else    asm volatile("s_waitcnt vmcnt(4)" ::: "memory");
          } else {
            asm volatile("s_waitcnt vmcnt(0)" ::: "memory");
          }
          bfrag A = {};
          if (l15 == 0) A = *(const bfrag*)(&x2bf[kc * 32 + qd * 8]);
          const short* bb = stgp(kc % 3);
#pragma unroll
          for (int i = 0; i < 4; ++i) {
            bfrag B = *(const bfrag*)(bb + i * 512 + lane * 8);
            acc[i] = __builtin_amdgcn_mfma_f32_16x16x32_bf16(A, B, acc[i], 0, 0, 0);
          }
          if (x7) {
            bfrag B = *(const bfrag*)(x7p(kc % 3) + lane * 8);
            e = __builtin_amdgcn_mfma_f32_16x16x32_bf16(A, B, e, 0, 0, 0);
          }
        }
        if (lane < 16)
#pragma unroll
          for (int i = 0; i < 4; ++i) {
            int n0 = (hb * 32 + w * 4 + i) * 16;
            mo[n0 + lane] = acc[i][0] + cb2[n0 + lane];
          }
      }
      if (w == 7 && lane < 16) mo[1024 + lane] = e[0] + cb2[1024 + lane];
    }
    __syncthreads();
    // ---- P5: mod = i_norm*(1+tanh(gamma)) + beta -> bf16 ----
    {
      float m2 = p.lnm[(size_t)t * cB + b];
      float r2 = p.lnr[(size_t)t * cB + b];
      float iv = __builtin_nontemporal_load(
          p.item_seq + (((size_t)b) * cT + t) * cD + tid);
      float inm = (iv - m2) * r2 * cn1g[tid] + cn1b[tid];
      modbf[tid] = f2bf(inm * (1.f + tanhf(mo[tid])) + mo[512 + tid]);
    }
    __syncthreads();
    // ---- P6: [k|v] = mod @ [Wk|Wv] (2 halves × 16 kc; 3-deep; ae folded) ---
    {
      f32x4 e = {};
#pragma unroll 1
      for (int hb = 0; hb < 2; ++hb) {
        const short* pk = hb ? p.pk_v : p.pk_k;
        const int base = hb ? 512 : 0;
        const bool x7 = (w == 7) && (hb == 0);
        f32x4 acc[4] = {};
#pragma unroll
        for (int g = 0; g < 2; ++g) {
          short* d = stgp(g);
#pragma unroll
          for (int i = 0; i < 4; ++i)
            stage_pk(pk, g * 32 + w * 4 + i, d + i * 512, lane);
          if (x7) stage_pk(p.pk_ae, g, x7p(g), lane);
        }
        for (int kc = 0; kc < 16; ++kc) {
          if (kc + 2 < 16) {
            short* dn = stgp((kc + 2) % 3);
#pragma unroll
            for (int i = 0; i < 4; ++i)
              stage_pk(pk, (kc + 2) * 32 + w * 4 + i, dn + i * 512, lane);
            if (x7) {
              stage_pk(p.pk_ae, kc + 2, x7p((kc + 2) % 3), lane);
              asm volatile("s_waitcnt vmcnt(10)" ::: "memory");
            } else {
              asm volatile("s_waitcnt vmcnt(8)" ::: "memory");
            }
          } else if (kc + 1 < 16) {
            if (x7) asm volatile("s_waitcnt vmcnt(5)" ::: "memory");
            else    asm volatile("s_waitcnt vmcnt(4)" ::: "memory");
          } else {
            asm volatile("s_waitcnt vmcnt(0)" ::: "memory");
          }
          bfrag A = {};
          if (l15 == 0) A = *(const bfrag*)(&modbf[kc * 32 + qd * 8]);
          const short* bb = stgp(kc % 3);
#pragma unroll
          for (int i = 0; i < 4; ++i) {
            bfrag B = *(const bfrag*)(bb + i * 512 + lane * 8);
            acc[i] = __builtin_amdgcn_mfma_f32_16x16x32_bf16(A, B, acc[i], 0, 0, 0);
          }
          if (x7) {
            bfrag B = *(const bfrag*)(x7p(kc % 3) + lane * 8);
            e = __builtin_amdgcn_mfma_f32_16x16x32_bf16(A, B, e, 0, 0, 0);
          }
        }
        if (lane < 16)
#pragma unroll
          for (int i = 0; i < 4; ++i) {
            int n0 = (w * 4 + i) * 16;
            kvb[base + n0 + lane] = acc[i][0];
          }
      }
      if (w == 7 && lane < 16) {
        if (lane < 8) {
          aeta[lane][0] = sigm(e[0] + cba[lane] + mo[1024 + lane]);
        } else {
          int hh = lane - 8;
          aeta[hh][1] = cSCALE * sigm(e[0] + cbe[hh] + mo[1032 + hh]);
        }
      }
    }
    __syncthreads();
    // ---- P7: state update (registers) + mem with q_{t+1} ----
    {
      float kvv = kvb[w * cDH + lane];
      float ks = kvv * kvv;
#pragma unroll
      for (int o = 32; o >= 1; o >>= 1) ks += __shfl_xor(ks, o);
      khat[w][lane] = kvv / fmaxf(sqrtf(ks), 1e-12f);
      float qv = bf2f(p.q_all[((size_t)(t + 1) * cB + b) * cD + w * cDH + lane]);
      float qs = qv * qv;
#pragma unroll
      for (int o = 32; o >= 1; o >>= 1) qs += __shfl_xor(qs, o);
      qh[w][lane] = qv / fmaxf(sqrtf(qs), 1e-12f);

      float vv = kvb[512 + w * cDH + lane];
      float al = aeta[w][0], et = aeta[w][1];
      float pred = 0.f;
#pragma unroll
      for (int j = 0; j < 64; j += 4) {
        float4 k4 = *(const float4*)&khat[w][j];
        pred += S[j] * k4.x + S[j + 1] * k4.y + S[j + 2] * k4.z + S[j + 3] * k4.w;
      }
      float f = et * (vv - pred), oma = 1.f - al;
      memv = 0.f;
#pragma unroll
      for (int j = 0; j < 64; j += 4) {
        float4 k4 = *(const float4*)&khat[w][j];
        float4 q4 = *(const float4*)&qh[w][j];
        S[j]     = oma * S[j]     + f * k4.x; memv += S[j]     * q4.x;
        S[j + 1] = oma * S[j + 1] + f * k4.y; memv += S[j + 1] * q4.y;
        S[j + 2] = oma * S[j + 2] + f * k4.z; memv += S[j + 2] * q4.z;
        S[j + 3] = oma * S[j + 3] + f * k4.w; memv += S[j + 3] * q4.w;
      }
      xcat_bf[512 + w * cDH + lane] = f2bf(memv);
    }
    __syncthreads();
  }

  // final memory read (slot 64 = last-item query) is in memv
  p.mem_ctx[(size_t)b * cD + w * cDH + lane] = memv;
}

// ======================= host launch ========================================
extern "C" void kernel_launch(void* const* d_in, const int* in_sizes, int n_in,
                              void* d_out, int out_size, void* d_ws, size_t ws_size,
                              hipStream_t stream) {
  (void)in_sizes; (void)n_in; (void)out_size;
  const float* item_seq   = (const float*)d_in[0];
  const float* user_stat  = (const float*)d_in[1];
  const float* last_item  = (const float*)d_in[2];
  const float* init_state = (const float*)d_in[3];
  const float* Wq  = (const float*)d_in[4];
  const float* Wk  = (const float*)d_in[5];
  const float* Wv  = (const float*)d_in[6];
  const float* Wa  = (const float*)d_in[7];
  const float* ba  = (const float*)d_in[8];
  const float* We  = (const float*)d_in[9];
  const float* be  = (const float*)d_in[10];
  const float* mcW1 = (const float*)d_in[11];
  const float* mcb1 = (const float*)d_in[12];
  const float* mcg  = (const float*)d_in[13];
  const float* mcbt = (const float*)d_in[14];
  const float* mcW2 = (const float*)d_in[15];
  const float* mcb2 = (const float*)d_in[16];
  const float* Wo  = (const float*)d_in[17];
  const float* bo  = (const float*)d_in[18];
  const float* W1  = (const float*)d_in[19];
  const float* b1  = (const float*)d_in[20];
  const float* W2  = (const float*)d_in[21];
  const float* b2  = (const float*)d_in[22];
  const float* n1g = (const float*)d_in[23];
  const float* n1b = (const float*)d_in[24];
  const float* n2g = (const float*)d_in[25];
  const float* n2b = (const float*)d_in[26];

  float* ws = (float*)d_ws;
  size_t off = 0;
  auto alloc = [&](size_t n) { float* p = ws + off; off += n; return p; };
  auto salloc = [&](size_t n) { return (short*)alloc((n + 1) / 2); };

  short* q_all   = salloc((size_t)(cT + 1) * cB * cD);
  float* lnm     = alloc((size_t)(cT + 1) * cB);
  float* lnr     = alloc((size_t)(cT + 1) * cB);
  float* us_norm = alloc((size_t)cB * cD);
  float* mem_ctx = alloc((size_t)cB * cD);
  float* x_buf   = alloc((size_t)cB * cD);
  float* xm      = alloc(cB);
  float* xr      = alloc(cB);
  float* u_buf   = alloc((size_t)cB * cFF);
  short* wt_q    = salloc((size_t)512 * 512);
  short* wt_m1   = salloc((size_t)512 * 1024);
  short* wt_m2   = salloc((size_t)1040 * 512);
  short* wt_k    = salloc((size_t)512 * 512);
  short* wt_v    = salloc((size_t)512 * 512);
  short* wt_ae   = salloc((size_t)16 * 512);
  short* wt_o    = salloc((size_t)512 * 512);
  short* wt_o_l  = salloc((size_t)512 * 512);
  short* wt_1    = salloc((size_t)2048 * 512);
  short* wt_1_l  = salloc((size_t)2048 * 512);
  short* wt_2    = salloc((size_t)512 * 2048);
  short* wt_2_l  = salloc((size_t)512 * 2048);
  // packed (scan consumption order)
  short* pk_m1   = salloc((size_t)32 * 32 * 512);
  short* pk_m2   = salloc((size_t)2 * 16 * 32 * 512);
  short* pk_m2x  = salloc((size_t)16 * 512);
  short* pk_k    = salloc((size_t)16 * 32 * 512);
  short* pk_v    = salloc((size_t)16 * 32 * 512);
  short* pk_ae   = salloc((size_t)16 * 512);
  if (ws_size < off * sizeof(float)) return;

  // --- prep: bf16 transposed weights ---
  tconv<<<dim3(16, 16), 256, 0, stream>>>(Wq, wt_q, 512, 512);
  tconv<<<dim3(32, 16), 256, 0, stream>>>(mcW1, wt_m1, 1024, 512);
  tconv<<<dim3(16, 33), 256, 0, stream>>>(mcW2, wt_m2, 512, 1040);
  tconv<<<dim3(16, 16), 256, 0, stream>>>(Wk, wt_k, 512, 512);
  tconv<<<dim3(16, 16), 256, 0, stream>>>(Wv, wt_v, 512, 512);
  tconv<<<dim3(16, 1), 256, 0, stream>>>(Wa, wt_ae, 512, 8);
  tconv<<<dim3(16, 1), 256, 0, stream>>>(We, wt_ae + (size_t)8 * 512, 512, 8);
  tconv2<<<dim3(16, 16), 256, 0, stream>>>(Wo, wt_o, wt_o_l, 512, 512);
  tconv2<<<dim3(16, 64), 256, 0, stream>>>(W1, wt_1, wt_1_l, 512, 2048);
  tconv2<<<dim3(64, 16), 256, 0, stream>>>(W2, wt_2, wt_2_l, 2048, 512);

  // --- pack weights into scan consumption order ---
  packw<<<dim3(256), 256, 0, stream>>>(wt_m1, pk_m1, 1024, 32, 32, 0);
  packw<<<dim3(128), 256, 0, stream>>>(wt_m2, pk_m2, 512, 16, 32, 0);
  packw<<<dim3(128), 256, 0, stream>>>(wt_m2, pk_m2 + (size_t)16 * 32 * 512,
                                       512, 16, 32, 512);
  packw<<<dim3(4), 256, 0, stream>>>(wt_m2, pk_m2x, 512, 16, 1, 1024);
  packw<<<dim3(128), 256, 0, stream>>>(wt_k, pk_k, 512, 16, 32, 0);
  packw<<<dim3(128), 256, 0, stream>>>(wt_v, pk_v, 512, 16, 32, 0);
  packw<<<dim3(4), 256, 0, stream>>>(wt_ae, pk_ae, 512, 16, 1, 0);

  ln_stats_k<<<(cT * cB + 2 * cB) / 4, 256, 0, stream>>>(
      item_seq, last_item, user_stat, n1g, n1b, lnm, lnr, us_norm);

  {  // q_all for all 65 slots (bf16 out)
    GemmArgs p{}; p.A = item_seq; p.A2 = last_item; p.sm = lnm; p.sr = lnr;
    p.g = n1g; p.b = n1b; p.WT = wt_q; p.Os = q_all;
    mgemm<MQ, 512><<<dim3(520, 8), 256, 0, stream>>>(p, 512);
  }

  {  // --- barrier-free scan: packed-coalesced 3-deep staged weights ---
    Scan2Params sp{};
    sp.item_seq = item_seq; sp.init_state = init_state; sp.us_norm = us_norm;
    sp.lnm = lnm; sp.lnr = lnr; sp.n1g = n1g; sp.n1b = n1b;
    sp.mcb1 = mcb1; sp.mcg = mcg; sp.mcbt = mcbt; sp.mcb2 = mcb2;
    sp.ba = ba; sp.be = be;
    sp.pk_m1 = pk_m1; sp.pk_m2 = pk_m2; sp.pk_m2x = pk_m2x;
    sp.pk_k = pk_k; sp.pk_v = pk_v; sp.pk_ae = pk_ae;
    sp.q_all = q_all;
    sp.mem_ctx = mem_ctx;
    scan1s_k<<<dim3(cB), dim3(512), 0, stream>>>(sp);
  }

  {  // x = user + mem_ctx @ Wo + bo  (split precision)
    GemmArgs p{}; p.A = mem_ctx; p.WT = wt_o; p.WT2 = wt_o_l;
    p.bias = bo; p.extra = user_stat; p.O = x_buf;
    pgemm<MWO, 512><<<dim3(8, 8), 256, 0, stream>>>(p, 512);
  }
  row_stats_k<<<cB / 4, 256, 0, stream>>>(x_buf, xm, xr);
  {  // u = relu(LN(x) @ W1 + b1)  (split precision)
    GemmArgs p{}; p.A = x_buf; p.sm = xm; p.sr = xr; p.g = n2g; p.b = n2b;
    p.WT = wt_1; p.WT2 = wt_1_l; p.bias = b1; p.O = u_buf;
    pgemm<MFF1, 512><<<dim3(8, 32), 256, 0, stream>>>(p, 512);
  }
  {  // out = x + u @ W2 + b2  (split precision)
    GemmArgs p{}; p.A = u_buf; p.WT = wt_2; p.WT2 = wt_2_l;
    p.bias = b2; p.extra = x_buf; p.O = (float*)d_out;
    pgemm<MFF2, 2048><<<dim3(8, 8), 256, 0, stream>>>(p, 2048);
  }
}